// Round 1
// baseline (238.532 us; speedup 1.0000x reference)
//
#include <hip/hip_runtime.h>
#include <math.h>

#define N_NODES 50000
#define N_EDGES 600000
#define NFEAT   256
#define NHID    128
#define NCLASS  40
#define NBUCK 196            // bucket = dst >> 8 (256-node windows)
#define EPB_A 2048           // edges per phase-A block
#define BUCK_CAP 4096        // staging capacity per bucket (mean ~3062)
#define BUCK_WIN 5888        // fixed CSR window per bucket >= BUCK_CAP + 7*256
#define BINA_BLOCKS ((N_EDGES + EPB_A - 1) / EPB_A)   // 293
#define CVTW_BLOCKS 224                               // 57344 weight elems / 256
#define GEMM_BLOCKS ((N_NODES + 63) / 64)             // 782

typedef __attribute__((ext_vector_type(8))) short bf16x8;
typedef __attribute__((ext_vector_type(4))) float f32x4;
typedef __attribute__((ext_vector_type(2))) float f32x2;

__device__ inline ushort f2bf(float f) {   // RNE, finite inputs
    uint u = __float_as_uint(f);
    uint r = (u + 0x7fffu + ((u >> 16) & 1u)) >> 16;
    return (ushort)r;
}

// ---------------------------------------------------------------------------
// K1: blocks [0, BINA_BLOCKS) bin edges by 256-node bucket into fixed-capacity
// staging regions (record: uint = (bf16(w)<<16) | src; entry {rec, dst&255}).
// Blocks [BINA_BLOCKS, +CVTW_BLOCKS) convert the three weight matrices to
// transposed bf16 (independent work overlapped in the same dispatch).
__global__ __launch_bounds__(256) void binA_cvtw(const int* __restrict__ src,
                                                 const int* __restrict__ dst,
                                                 const float* __restrict__ w,
                                                 int* __restrict__ bucket_cnt,
                                                 int2* __restrict__ staging, int E,
                                                 const float* __restrict__ W1,
                                                 const float* __restrict__ W2,
                                                 const float* __restrict__ W3,
                                                 ushort* __restrict__ BT1,
                                                 ushort* __restrict__ BT2,
                                                 ushort* __restrict__ BT3) {
    int tid = threadIdx.x;
    if ((int)blockIdx.x >= BINA_BLOCKS) {
        int idx = ((int)blockIdx.x - BINA_BLOCKS) * 256 + tid;
        if (idx < 32768) {                       // BT1: 128x256 from W1[256x128]
            int nr = idx >> 8, k = idx & 255;
            BT1[idx] = f2bf(W1[(size_t)k * 128 + nr]);
        } else if (idx < 49152) {                // BT2: 128x128 from W2[128x128]
            int t = idx - 32768;
            int nr = t >> 7, k = t & 127;
            BT2[t] = f2bf(W2[(size_t)k * 128 + nr]);
        } else if (idx < 57344) {                // BT3: 64x128 from W3[128x40], zero-padded
            int t = idx - 49152;
            int nr = t >> 7, k = t & 127;
            BT3[t] = (nr < 40) ? f2bf(W3[(size_t)k * 40 + nr]) : (ushort)0;
        }
        return;
    }
    __shared__ int lh[NBUCK];
    for (int b = tid; b < NBUCK; b += 256) lh[b] = 0;
    __syncthreads();
    int base = blockIdx.x * EPB_A;
    int d[8];
    #pragma unroll
    for (int j = 0; j < 8; ++j) {
        int i = base + j * 256 + tid;
        d[j] = (i < E) ? dst[i] : -1;
        if (d[j] >= 0) atomicAdd(&lh[d[j] >> 8], 1);
    }
    __syncthreads();
    for (int b = tid; b < NBUCK; b += 256) {
        int c = lh[b];
        lh[b] = c ? (b * BUCK_CAP + atomicAdd(&bucket_cnt[b], c)) : 0;
    }
    __syncthreads();
    #pragma unroll
    for (int j = 0; j < 8; ++j) {
        int i = base + j * 256 + tid;
        if (d[j] >= 0) {
            int slot = atomicAdd(&lh[d[j] >> 8], 1);
            uint rec = ((uint)f2bf(w[i]) << 16) | (uint)src[i];
            staging[slot] = make_int2((int)rec, d[j] & 255);
        }
    }
}

// ---------------------------------------------------------------------------
// bf16 MFMA GEMM body: C[M x Nout] = A[M x K] @ BT[.. x K]^T, one 64-row tile.
template<int NT, bool OUTBF, bool AF32>
__device__ __forceinline__ void gemm_body(const void* __restrict__ Ain,
                                          const ushort* __restrict__ BT,
                                          int M, int K, int Nout,
                                          void* __restrict__ Cout, int row0) {
    __shared__ ushort a_s[64 * 40];
    __shared__ ushort b_s[64 * NT * 40];
    int tid = threadIdx.x;
    int wave = tid >> 6, lane = tid & 63;
    int lr = lane & 15, lk = (lane >> 4) * 8;
    f32x4 acc[4][NT];
    #pragma unroll
    for (int mt = 0; mt < 4; ++mt)
        #pragma unroll
        for (int nt = 0; nt < NT; ++nt) acc[mt][nt] = (f32x4){0.f, 0.f, 0.f, 0.f};

    for (int k0 = 0; k0 < K; k0 += 32) {
        {   // A tile: 64 rows x 32 k, 8 elems/thread
            int r = tid >> 2, c8 = (tid & 3) * 8;
            int gr = row0 + r; if (gr >= M) gr = M - 1;  // clamp, store-guarded
            if (AF32) {
                const float* Af = (const float*)Ain;
                float4 v0 = *(const float4*)(Af + (size_t)gr * K + k0 + c8);
                float4 v1 = *(const float4*)(Af + (size_t)gr * K + k0 + c8 + 4);
                ushort4 o0, o1;
                o0.x = f2bf(v0.x); o0.y = f2bf(v0.y); o0.z = f2bf(v0.z); o0.w = f2bf(v0.w);
                o1.x = f2bf(v1.x); o1.y = f2bf(v1.y); o1.z = f2bf(v1.z); o1.w = f2bf(v1.w);
                *(ushort4*)(a_s + r * 40 + c8) = o0;
                *(ushort4*)(a_s + r * 40 + c8 + 4) = o1;
            } else {
                const ushort* Ab = (const ushort*)Ain;
                float4 v = *(const float4*)(Ab + (size_t)gr * K + k0 + c8);
                *(float4*)(a_s + r * 40 + c8) = v;
            }
        }
        #pragma unroll
        for (int i = 0; i < NT; ++i) {  // BT tile: 64*NT rows x 32 k
            int idx = tid * NT + i;
            int r = idx >> 2, c8 = (idx & 3) * 8;
            float4 v = *(const float4*)(BT + (size_t)r * K + k0 + c8);
            *(float4*)(b_s + r * 40 + c8) = v;
        }
        __syncthreads();
        bf16x8 bfr[NT];
        #pragma unroll
        for (int nt = 0; nt < NT; ++nt)
            bfr[nt] = *(const bf16x8*)(b_s + ((wave * NT + nt) * 16 + lr) * 40 + lk);
        #pragma unroll
        for (int mt = 0; mt < 4; ++mt) {
            bf16x8 afr = *(const bf16x8*)(a_s + (mt * 16 + lr) * 40 + lk);
            #pragma unroll
            for (int nt = 0; nt < NT; ++nt)
                acc[mt][nt] = __builtin_amdgcn_mfma_f32_16x16x32_bf16(
                    afr, bfr[nt], acc[mt][nt], 0, 0, 0);
        }
        __syncthreads();
    }
    // C/D layout: col = lane&15, row = (lane>>4)*4 + i
    int col0 = wave * NT * 16;
    #pragma unroll
    for (int mt = 0; mt < 4; ++mt) {
        int gr0 = row0 + mt * 16 + (lane >> 4) * 4;
        #pragma unroll
        for (int nt = 0; nt < NT; ++nt) {
            int gc = col0 + nt * 16 + lr;
            #pragma unroll
            for (int i = 0; i < 4; ++i) {
                int gr = gr0 + i;
                if (gr < M && gc < Nout) {
                    if (OUTBF)
                        ((ushort*)Cout)[(size_t)gr * Nout + gc] = f2bf(acc[mt][nt][i]);
                    else
                        ((float*)Cout)[(size_t)gr * Nout + gc] = acc[mt][nt][i];
                }
            }
        }
    }
}

template<int NT, bool OUTBF, bool AF32>
__global__ __launch_bounds__(256) void gemm_mfma(const void* __restrict__ Ain,
                                                 const ushort* __restrict__ BT,
                                                 int M, int K, int Nout,
                                                 void* __restrict__ Cout) {
    gemm_body<NT, OUTBF, AF32>(Ain, BT, M, K, Nout, Cout, blockIdx.x * 64);
}

// ---------------------------------------------------------------------------
// K2: blocks [0, NBUCK) do self-contained per-bucket scan+scatter into FIXED
// windows (base = b*BUCK_WIN; inter-bucket gaps are never read -> no global
// prefix needed; per-node {start,end} stored as int2). Blocks [NBUCK, +782)
// run GEMM1 (x fp32 -> supA bf16), fully overlapping the CSR tail.
__global__ __launch_bounds__(256) void scan_gemm1(const int* __restrict__ bucket_cnt,
                                                  const int2* __restrict__ staging,
                                                  int2* __restrict__ rsp2,
                                                  uint* __restrict__ edges,
                                                  const float* __restrict__ x,
                                                  const ushort* __restrict__ BT1,
                                                  ushort* __restrict__ supA) {
    if ((int)blockIdx.x >= NBUCK) {
        gemm_body<2, true, true>(x, BT1, N_NODES, 256, 128, supA,
                                 ((int)blockIdx.x - NBUCK) * 64);
        return;
    }
    __shared__ int hist[256];
    __shared__ int buf[256];
    __shared__ int lcur[256];
    int tid = threadIdx.x;
    hist[tid] = 0;
    __syncthreads();
    int b = blockIdx.x;
    int c = bucket_cnt[b];
    const int2* st = staging + (size_t)b * BUCK_CAP;
    for (int p = tid; p < c; p += 256) atomicAdd(&hist[st[p].y], 1);
    __syncthreads();
    int v = (hist[tid] + 7) & ~7;   // pad per-node count to multiple of 8
    buf[tid] = v;
    __syncthreads();
    #pragma unroll
    for (int off = 1; off < 256; off <<= 1) {
        int t = (tid >= off) ? buf[tid - off] : 0;
        __syncthreads();
        buf[tid] += t;
        __syncthreads();
    }
    int bb = b * BUCK_WIN;
    int ex = buf[tid] - v + bb;
    int i = b * 256 + tid;
    if (i < N_NODES) rsp2[i] = make_int2(ex, ex + v);
    lcur[tid] = ex;
    __syncthreads();
    int e0 = bb + buf[255];
    for (int p = bb + tid; p < e0; p += 256) edges[p] = 0;   // covers padding
    __syncthreads();
    for (int p = tid; p < c; p += 256) {
        int2 r = st[p];
        int slot = atomicAdd(&lcur[r.y], 1);
        edges[slot] = (uint)r.x;
    }
}

// ---------------------------------------------------------------------------
// SpMM over bf16 support, F=128. Wave = 1 node; 4 edges per wave-iteration:
// slot = lane>>4 picks the edge, fb = lane&15 picks a 16B (8-feature) chunk.
// One dwordx4 gather per 4 edges (4x fewer VMEM instructions than per-edge
// dword gathers, same bytes). Cross-slot shfl_xor reduction at the end.
__global__ __launch_bounds__(256) void spmm128v(const uint4* __restrict__ sup4,
                                                const int2* __restrict__ rsp2,
                                                const uint* __restrict__ edges,
                                                const float* __restrict__ bias,
                                                uint4* __restrict__ outb4, int n) {
    int wid = blockIdx.x * 4 + (threadIdx.x >> 6);
    int lane = threadIdx.x & 63;
    if (wid >= n) return;
    int2 ke = rsp2[wid];
    int k = ke.x, e = ke.y;
    int slot = lane >> 4, fb = lane & 15;
    f32x2 a0 = (f32x2){0.f, 0.f}, a1 = a0, a2 = a0, a3 = a0;
    if (k < e) {
        uint rec = edges[k + slot];
        int k1 = (k + 4 < e) ? k + 4 : k;
        uint recn = edges[k1 + slot];
        uint4 p = sup4[(size_t)(rec & 0xffffu) * 16 + fb];
        for (; k < e; k += 4) {
            int k2 = (k + 8 < e) ? k + 8 : k;           // clamp: reload (L1 hit)
            uint recnn = edges[k2 + slot];
            uint4 pn = sup4[(size_t)(recn & 0xffffu) * 16 + fb];
            float w = __uint_as_float(rec & 0xffff0000u);   // bf16 bits -> f32
            f32x2 wv = (f32x2){w, w};
            f32x2 v;
            v.x = __uint_as_float(p.x << 16); v.y = __uint_as_float(p.x & 0xffff0000u);
            a0 += v * wv;
            v.x = __uint_as_float(p.y << 16); v.y = __uint_as_float(p.y & 0xffff0000u);
            a1 += v * wv;
            v.x = __uint_as_float(p.z << 16); v.y = __uint_as_float(p.z & 0xffff0000u);
            a2 += v * wv;
            v.x = __uint_as_float(p.w << 16); v.y = __uint_as_float(p.w & 0xffff0000u);
            a3 += v * wv;
            rec = recn; recn = recnn; p = pn;
        }
    }
    #pragma unroll
    for (int off = 16; off <= 32; off <<= 1) {
        a0.x += __shfl_xor(a0.x, off, 64); a0.y += __shfl_xor(a0.y, off, 64);
        a1.x += __shfl_xor(a1.x, off, 64); a1.y += __shfl_xor(a1.y, off, 64);
        a2.x += __shfl_xor(a2.x, off, 64); a2.y += __shfl_xor(a2.y, off, 64);
        a3.x += __shfl_xor(a3.x, off, 64); a3.y += __shfl_xor(a3.y, off, 64);
    }
    if (slot == 0) {
        float4 bl = *(const float4*)(bias + fb * 8);
        float4 bh = *(const float4*)(bias + fb * 8 + 4);
        uint4 o;
        o.x = ((uint)f2bf(fmaxf(a0.y + bl.y, 0.f)) << 16) | (uint)f2bf(fmaxf(a0.x + bl.x, 0.f));
        o.y = ((uint)f2bf(fmaxf(a1.y + bl.w, 0.f)) << 16) | (uint)f2bf(fmaxf(a1.x + bl.z, 0.f));
        o.z = ((uint)f2bf(fmaxf(a2.y + bh.y, 0.f)) << 16) | (uint)f2bf(fmaxf(a2.x + bh.x, 0.f));
        o.w = ((uint)f2bf(fmaxf(a3.y + bh.w, 0.f)) << 16) | (uint)f2bf(fmaxf(a3.x + bh.z, 0.f));
        outb4[(size_t)wid * 16 + fb] = o;
    }
}

// Layer 3: F=64 (sup3 zero-padded past class 40). 8 edges per wave-iteration:
// slot = lane>>3, fb = lane&7; one dwordx4 gather per 8 edges. Fused bias +
// log_softmax over the 40 valid classes.
__global__ __launch_bounds__(256) void spmm64_lsm(const uint4* __restrict__ sup4,
                                                  const int2* __restrict__ rsp2,
                                                  const uint* __restrict__ edges,
                                                  const float* __restrict__ bias,
                                                  float* __restrict__ out, int n) {
    int wid = blockIdx.x * 4 + (threadIdx.x >> 6);
    int lane = threadIdx.x & 63;
    if (wid >= n) return;
    int2 ke = rsp2[wid];
    int k = ke.x, e = ke.y;
    int slot = lane >> 3, fb = lane & 7;
    f32x2 a0 = (f32x2){0.f, 0.f}, a1 = a0, a2 = a0, a3 = a0;
    if (k < e) {
        uint rec = edges[k + slot];
        int k1 = (k + 8 < e) ? k + 8 : k;
        uint recn = edges[k1 + slot];
        uint4 p = sup4[(size_t)(rec & 0xffffu) * 8 + fb];
        for (; k < e; k += 8) {
            int k2 = (k + 16 < e) ? k + 16 : k;
            uint recnn = edges[k2 + slot];
            uint4 pn = sup4[(size_t)(recn & 0xffffu) * 8 + fb];
            float w = __uint_as_float(rec & 0xffff0000u);
            f32x2 wv = (f32x2){w, w};
            f32x2 v;
            v.x = __uint_as_float(p.x << 16); v.y = __uint_as_float(p.x & 0xffff0000u);
            a0 += v * wv;
            v.x = __uint_as_float(p.y << 16); v.y = __uint_as_float(p.y & 0xffff0000u);
            a1 += v * wv;
            v.x = __uint_as_float(p.z << 16); v.y = __uint_as_float(p.z & 0xffff0000u);
            a2 += v * wv;
            v.x = __uint_as_float(p.w << 16); v.y = __uint_as_float(p.w & 0xffff0000u);
            a3 += v * wv;
            rec = recn; recn = recnn; p = pn;
        }
    }
    #pragma unroll
    for (int off = 8; off <= 32; off <<= 1) {
        a0.x += __shfl_xor(a0.x, off, 64); a0.y += __shfl_xor(a0.y, off, 64);
        a1.x += __shfl_xor(a1.x, off, 64); a1.y += __shfl_xor(a1.y, off, 64);
        a2.x += __shfl_xor(a2.x, off, 64); a2.y += __shfl_xor(a2.y, off, 64);
        a3.x += __shfl_xor(a3.x, off, 64); a3.y += __shfl_xor(a3.y, off, 64);
    }
    // every lane now holds full sums for features fb*8 .. fb*8+7
    float vv[8];
    bool valid = (fb < 5);           // classes 0..39 live in fb 0..4
    if (valid) {
        float4 bl = *(const float4*)(bias + fb * 8);
        float4 bh = *(const float4*)(bias + fb * 8 + 4);
        vv[0] = a0.x + bl.x; vv[1] = a0.y + bl.y;
        vv[2] = a1.x + bl.z; vv[3] = a1.y + bl.w;
        vv[4] = a2.x + bh.x; vv[5] = a2.y + bh.y;
        vv[6] = a3.x + bh.z; vv[7] = a3.y + bh.w;
    } else {
        #pragma unroll
        for (int j = 0; j < 8; ++j) vv[j] = -INFINITY;
    }
    float m = vv[0];
    #pragma unroll
    for (int j = 1; j < 8; ++j) m = fmaxf(m, vv[j]);
    #pragma unroll
    for (int off = 1; off <= 4; off <<= 1) m = fmaxf(m, __shfl_xor(m, off, 64));
    float s = 0.f;
    if (valid) {
        #pragma unroll
        for (int j = 0; j < 8; ++j) s += expf(vv[j] - m);
    }
    #pragma unroll
    for (int off = 1; off <= 4; off <<= 1) s += __shfl_xor(s, off, 64);
    float ls = logf(s) + m;
    if (slot == 0 && valid) {
        float4 r0 = make_float4(vv[0] - ls, vv[1] - ls, vv[2] - ls, vv[3] - ls);
        float4 r1 = make_float4(vv[4] - ls, vv[5] - ls, vv[6] - ls, vv[7] - ls);
        *(float4*)(out + (size_t)wid * 40 + fb * 8) = r0;
        *(float4*)(out + (size_t)wid * 40 + fb * 8 + 4) = r1;
    }
}

// ---------------------------------------------------------------------------
extern "C" void kernel_launch(void* const* d_in, const int* in_sizes, int n_in,
                              void* d_out, int out_size, void* d_ws, size_t ws_size,
                              hipStream_t stream) {
    const float* x   = (const float*)d_in[0];
    const float* ew  = (const float*)d_in[1];
    const float* W1  = (const float*)d_in[2];
    const float* b1  = (const float*)d_in[3];
    const float* W2  = (const float*)d_in[4];
    const float* b2  = (const float*)d_in[5];
    const float* W3  = (const float*)d_in[6];
    const float* b3  = (const float*)d_in[7];
    const int* esrc  = (const int*)d_in[8];
    const int* edst  = (const int*)d_in[9];
    float* out = (float*)d_out;

    char* ws = (char*)d_ws;
    size_t off = 0;
    auto alloc = [&](size_t bytes) {
        size_t cur = off;
        off += (bytes + 255) & ~(size_t)255;
        return cur;
    };
    int* bucket_cnt = (int*)(ws + alloc(256 * sizeof(int)));
    int2* rsp2   = (int2*)(ws + alloc((size_t)N_NODES * sizeof(int2)));          // 400 KB
    uint* edges  = (uint*)(ws + alloc((size_t)NBUCK * BUCK_WIN * sizeof(uint))); // 4.6 MB
    int2* staging = (int2*)(ws + alloc((size_t)NBUCK * BUCK_CAP * sizeof(int2))); // 6.4 MB
    ushort* BT1  = (ushort*)(ws + alloc(128 * 256 * 2));
    ushort* BT2  = (ushort*)(ws + alloc(128 * 128 * 2));
    ushort* BT3  = (ushort*)(ws + alloc(64 * 128 * 2));
    char* Sreg   = ws + alloc((size_t)N_NODES * 128 * 2);       // 12.8 MB
    char* Hreg   = ws + alloc((size_t)N_NODES * 128 * 2);       // 12.8 MB
    char* Treg   = ws + alloc((size_t)N_NODES * 128 * 2);       // 12.8 MB

    ushort* supA = (ushort*)Sreg;                  // gemm1 out
    ushort* hA   = (ushort*)Hreg;                  // spmm1 out
    ushort* supB = (ushort*)Treg;                  // gemm2 out
    ushort* hB   = (ushort*)Sreg;                  // spmm2 out (supA dead)
    ushort* sup3 = (ushort*)Treg;                  // gemm3 out F=64 (supB dead)

    hipMemsetAsync(bucket_cnt, 0, 256 * sizeof(int), stream);
    // K1: edge binning || weight conversion
    binA_cvtw<<<BINA_BLOCKS + CVTW_BLOCKS, 256, 0, stream>>>(
        esrc, edst, ew, bucket_cnt, staging, N_EDGES, W1, W2, W3, BT1, BT2, BT3);
    // K2: per-bucket scan+scatter (fixed windows) || GEMM1
    scan_gemm1<<<NBUCK + GEMM_BLOCKS, 256, 0, stream>>>(
        bucket_cnt, staging, rsp2, edges, x, BT1, supA);

    int spmm_blocks = (N_NODES + 3) / 4;     // 12500
    // layer 1 aggregate + relu
    spmm128v<<<spmm_blocks, 256, 0, stream>>>((const uint4*)supA, rsp2, edges, b1,
                                              (uint4*)hA, N_NODES);
    // layer 2
    gemm_mfma<2, true, false><<<GEMM_BLOCKS, 256, 0, stream>>>(hA, BT2, N_NODES, 128,
                                                               128, supB);
    spmm128v<<<spmm_blocks, 256, 0, stream>>>((const uint4*)supB, rsp2, edges, b2,
                                              (uint4*)hB, N_NODES);
    // layer 3 (Nout=64 zero-padded; BT3 rows 40..63 are zero)
    gemm_mfma<1, true, false><<<GEMM_BLOCKS, 256, 0, stream>>>(hB, BT3, N_NODES, 128,
                                                               64, sup3);
    spmm64_lsm<<<spmm_blocks, 256, 0, stream>>>((const uint4*)sup3, rsp2, edges, b3,
                                                out, N_NODES);
}